// Round 2
// baseline (1225.386 us; speedup 1.0000x reference)
//
#include <hip/hip_runtime.h>
#include <math.h>

#define HWPIX 3136   // 56*56
#define CH    256
#define NB    16
#define IMG   224
#define TY    4      // output rows per tail block

// Normalized Gaussian weights: sigma=4, radius=16, 2*sigma^2=32.
// Matches reference f32 computation to ~1e-7 relative.
__constant__ float GW[33] = {
    3.3458800e-05f, 8.8152100e-05f, 2.1817847e-04f, 5.0728021e-04f,
    1.1080013e-03f, 2.2734742e-03f, 4.3822299e-03f, 7.9351934e-03f,
    1.3498218e-02f, 2.1570092e-02f, 3.2380543e-02f, 4.5663884e-02f,
    6.0494818e-02f, 7.5287016e-02f, 8.8019438e-02f, 9.6670425e-02f,
    9.9739093e-02f, 9.6670425e-02f, 8.8019438e-02f, 7.5287016e-02f,
    6.0494818e-02f, 4.5663884e-02f, 3.2380543e-02f, 2.1570092e-02f,
    1.3498218e-02f, 7.9351934e-03f, 4.3822299e-03f, 2.2734742e-03f,
    1.1080013e-03f, 5.0728021e-04f, 2.1817847e-04f, 8.8152100e-05f,
    3.3458800e-05f
};

// ---------------- Kernel 1: per-pixel Mahalanobis quadratic form ----------------
// grid = 3136 blocks (one per pixel), block = 256 threads = 4 waves.
// Wave w handles rows d in [64w, 64w+64); lane l handles columns c = 4l..4l+3.
// acc[b][c] += M[d][c] * diff[b][d]   (quad invariant under M transpose)
//
// Memory-latency fix vs previous version: depth-4 rotating register prefetch of
// M rows (>=4 KB wave-wide in flight) + __launch_bounds__(256,4) pinning
// 4 waves/SIMD so the CU keeps ~64 KB of HBM reads outstanding.

#define MAHAL_ROW(D, MVEC)                                                       \
    {                                                                            \
        const float4* sdv = reinterpret_cast<const float4*>(&sdiff[(D) * 20]);   \
        const float4 dv0 = sdv[0], dv1 = sdv[1], dv2 = sdv[2], dv3 = sdv[3];     \
        const float dsv[16] = {dv0.x, dv0.y, dv0.z, dv0.w,                       \
                               dv1.x, dv1.y, dv1.z, dv1.w,                       \
                               dv2.x, dv2.y, dv2.z, dv2.w,                       \
                               dv3.x, dv3.y, dv3.z, dv3.w};                      \
        _Pragma("unroll")                                                        \
        for (int b = 0; b < NB; ++b) {                                           \
            const float s = dsv[b];                                              \
            acc[b].x = fmaf((MVEC).x, s, acc[b].x);                              \
            acc[b].y = fmaf((MVEC).y, s, acc[b].y);                              \
            acc[b].z = fmaf((MVEC).z, s, acc[b].z);                              \
            acc[b].w = fmaf((MVEC).w, s, acc[b].w);                              \
        }                                                                        \
    }

__global__ __launch_bounds__(256, 4)
void mahal_kernel(const float* __restrict__ inputs,   // [16][3136][256]
                  const float* __restrict__ mean,     // [3136][256]
                  const float* __restrict__ cvar,     // [3136][256][256]
                  float* __restrict__ mask_small)     // [16][3136]
{
    const int p    = blockIdx.x;
    const int tid  = threadIdx.x;
    const int lane = tid & 63;
    const int w    = tid >> 6;

    // diff staged as [c][b] with stride 20 floats (80 B -> 16B aligned rows).
    // Main-loop reads are wave-uniform float4 -> LDS broadcast, conflict-free.
    __shared__ float sdiff[CH * 20];
    __shared__ float sred[4][16];

    const float* mrow_mean = mean + (size_t)p * CH;

    {
        const float mv = mrow_mean[tid];
        #pragma unroll
        for (int b = 0; b < NB; ++b) {
            sdiff[tid * 20 + b] = inputs[((size_t)b * HWPIX + p) * CH + tid] - mv;
        }
    }
    __syncthreads();

    const int c4   = lane * 4;
    const int row0 = w << 6;
    // per-wave base pointer computed ONCE; loop addressing is int offsets only
    const float* Mb = cvar + (size_t)p * CH * CH + (size_t)row0 * CH + c4;

    float4 acc[NB];
    #pragma unroll
    for (int b = 0; b < NB; ++b) acc[b] = make_float4(0.f, 0.f, 0.f, 0.f);

    // rotating prefetch registers: mr[i] holds row (kk + i)
    float4 mr[4];
    #pragma unroll
    for (int i = 0; i < 4; ++i)
        mr[i] = *reinterpret_cast<const float4*>(Mb + i * CH);

    // kk = 0,4,...,56 : compute rows kk..kk+3, prefetch rows kk+4..kk+7 (<=63)
    #pragma unroll 3
    for (int kk = 0; kk < 60; kk += 4) {
        #pragma unroll
        for (int i = 0; i < 4; ++i) {
            const float4 m = mr[i];
            mr[i] = *reinterpret_cast<const float4*>(Mb + (kk + 4 + i) * CH);
            MAHAL_ROW(row0 + kk + i, m)
        }
    }
    // peeled tail: rows 60..63, no prefetch (avoids OOB read past cvar)
    #pragma unroll
    for (int i = 0; i < 4; ++i) {
        MAHAL_ROW(row0 + 60 + i, mr[i])
    }

    // epilogue: q[b] = sum_c acc[b][c] * diff[b][c] (re-read diff coalesced, L2-hot)
    const float4 mn = *reinterpret_cast<const float4*>(mrow_mean + c4);
    float q[NB];
    #pragma unroll
    for (int b = 0; b < NB; ++b) {
        const float4 f = *reinterpret_cast<const float4*>(inputs + ((size_t)b * HWPIX + p) * CH + c4);
        const float4 df = make_float4(f.x - mn.x, f.y - mn.y, f.z - mn.z, f.w - mn.w);
        q[b] = acc[b].x * df.x + acc[b].y * df.y + acc[b].z * df.z + acc[b].w * df.w;
    }

    // 64-lane butterfly reduce per b, then cross-wave via LDS
    #pragma unroll
    for (int b = 0; b < NB; ++b) {
        float v = q[b];
        for (int off = 32; off > 0; off >>= 1) v += __shfl_xor(v, off, 64);
        if (lane == 0) sred[w][b] = v;
    }
    __syncthreads();
    if (tid < NB) {
        const float s = sred[0][tid] + sred[1][tid] + sred[2][tid] + sred[3][tid];
        mask_small[(size_t)tid * HWPIX + p] = sqrtf(fmaxf(s, 0.0f));
    }
}

// ---------------- Kernel 2: fused resize(56->224) + blurH + blurW + max ----------
// grid = (56 y-tiles, 16 batches), block = 256 threads.
// Per block: stage resized rows [y0-16, y0+TY+16) in LDS (bilinear straight from
// mask_small, which is 12.5 KB/batch and L1/L2-resident), H-blur into LDS,
// W-blur to output + per-batch max. Reflect-101 on both axes.
__global__ void tail_kernel(const float* __restrict__ small_,   // [16][3136]
                            float* __restrict__ mask_out,       // [16][224][224]
                            float* __restrict__ score)          // [16]
{
    const int b   = blockIdx.y;
    const int y0  = blockIdx.x * TY;
    const int tid = threadIdx.x;

    __shared__ float S[TY + 32][IMG];   // resized rows (reflected)
    __shared__ float Hb[TY][IMG];       // H-blurred rows
    __shared__ float m4[4];

    const float* s = small_ + (size_t)b * HWPIX;

    // stage resized rows y0-16 .. y0+TY+15  (36 x 224 values)
    for (int idx = tid; idx < (TY + 32) * IMG; idx += 256) {
        const int r = idx / IMG;
        const int x = idx - r * IMG;
        int y = y0 - 16 + r;                          // in [-16, 239]
        y = y < 0 ? -y : (y > 223 ? 446 - y : y);     // reflect-101
        float fy = y * 0.25f - 0.375f;
        float fx = x * 0.25f - 0.375f;
        fy = fminf(fmaxf(fy, 0.0f), 55.0f);
        fx = fminf(fmaxf(fx, 0.0f), 55.0f);
        const int iy0 = min((int)fy, 54);
        const int ix0 = min((int)fx, 54);
        const float wy = fy - iy0;
        const float wx = fx - ix0;
        const float v00 = s[iy0 * 56 + ix0];
        const float v01 = s[iy0 * 56 + ix0 + 1];
        const float v10 = s[(iy0 + 1) * 56 + ix0];
        const float v11 = s[(iy0 + 1) * 56 + ix0 + 1];
        const float v0 = v00 + wx * (v01 - v00);
        const float v1 = v10 + wx * (v11 - v10);
        S[r][x] = v0 + wy * (v1 - v0);
    }
    __syncthreads();

    // blur along H: Hb[ty][x] = sum_i GW[i] * S[ty+i][x]
    for (int idx = tid; idx < TY * IMG; idx += 256) {
        const int ty = idx / IMG;
        const int x  = idx - ty * IMG;
        float a = 0.f;
        #pragma unroll
        for (int i = 0; i < 33; ++i) a = fmaf(GW[i], S[ty + i][x], a);
        Hb[ty][x] = a;
    }
    __syncthreads();

    // blur along W + store + max
    float vmax = 0.f;
    for (int idx = tid; idx < TY * IMG; idx += 256) {
        const int ty = idx / IMG;
        const int x  = idx - ty * IMG;
        float a = 0.f;
        #pragma unroll
        for (int i = 0; i < 33; ++i) {
            int xx = x - 16 + i;
            xx = xx < 0 ? -xx : (xx > 223 ? 446 - xx : xx);
            a = fmaf(GW[i], Hb[ty][xx], a);
        }
        mask_out[((size_t)b * IMG + (y0 + ty)) * IMG + x] = a;
        vmax = fmaxf(vmax, a);
    }

    // block max -> atomicMax (values >= 0, int-bit compare is monotone)
    for (int off = 32; off > 0; off >>= 1) vmax = fmaxf(vmax, __shfl_xor(vmax, off, 64));
    const int lane = tid & 63;
    const int wv   = tid >> 6;
    if (lane == 0) m4[wv] = vmax;
    __syncthreads();
    if (tid == 0) {
        const float mm = fmaxf(fmaxf(m4[0], m4[1]), fmaxf(m4[2], m4[3]));
        atomicMax(reinterpret_cast<int*>(score) + b, __float_as_int(mm));
    }
}

// ---------------- Kernel 0: init score to 0 (d_out is poisoned 0xAA) ----------------
__global__ void init_score(float* __restrict__ score)
{
    if (threadIdx.x < NB) score[threadIdx.x] = 0.0f;
}

extern "C" void kernel_launch(void* const* d_in, const int* in_sizes, int n_in,
                              void* d_out, int out_size, void* d_ws, size_t ws_size,
                              hipStream_t stream)
{
    const float* inputs = (const float*)d_in[0];   // [16][3136][256]
    const float* mean   = (const float*)d_in[1];   // [3136][256]
    const float* cvar   = (const float*)d_in[2];   // [3136][256][256]

    float* score    = (float*)d_out;               // [16]
    float* mask_out = (float*)d_out + NB;          // [16][224][224]

    float* mask_small = (float*)d_ws;              // 16*3136 floats

    init_score  <<<1, 64, 0, stream>>>(score);
    mahal_kernel<<<HWPIX, 256, 0, stream>>>(inputs, mean, cvar, mask_small);
    tail_kernel <<<dim3(IMG / TY, NB), 256, 0, stream>>>(mask_small, mask_out, score);
}

// Round 3
// 1080.762 us; speedup vs baseline: 1.1338x; 1.1338x over previous
//
#include <hip/hip_runtime.h>
#include <math.h>

#define HWPIX 3136   // 56*56
#define CH    256
#define NB    16
#define IMG   224
#define TY    16     // output rows per tail block (halo redundancy (TY+32)/TY = 3x)

// Normalized Gaussian weights: sigma=4, radius=16, 2*sigma^2=32.
// Matches reference f32 computation to ~1e-7 relative.
__constant__ float GW[33] = {
    3.3458800e-05f, 8.8152100e-05f, 2.1817847e-04f, 5.0728021e-04f,
    1.1080013e-03f, 2.2734742e-03f, 4.3822299e-03f, 7.9351934e-03f,
    1.3498218e-02f, 2.1570092e-02f, 3.2380543e-02f, 4.5663884e-02f,
    6.0494818e-02f, 7.5287016e-02f, 8.8019438e-02f, 9.6670425e-02f,
    9.9739093e-02f, 9.6670425e-02f, 8.8019438e-02f, 7.5287016e-02f,
    6.0494818e-02f, 4.5663884e-02f, 3.2380543e-02f, 2.1570092e-02f,
    1.3498218e-02f, 7.9351934e-03f, 4.3822299e-03f, 2.2734742e-03f,
    1.1080013e-03f, 5.0728021e-04f, 2.1817847e-04f, 8.8152100e-05f,
    3.3458800e-05f
};

// ---------------- Kernel 1: per-pixel Mahalanobis quadratic form ----------------
// grid = 3136 blocks (one per pixel), block = 256 threads = 4 waves.
// Wave w handles rows d in [64w, 64w+64); lane l handles columns c = 4l..4l+3.
// acc[b][c] += M[d][c] * diff[b][d]   (quad invariant under M transpose)
//
// launch_bounds(256,2): VGPR cap 256 (NOT 128 — the 128 cap spilled last round),
// 2 blocks/CU = 8 waves/CU. Depth-4 rotating register prefetch keeps ~4 KB/wave
// (32 KB/CU) of HBM reads in flight; loads are spaced by 64 FMAs (128 cy) so the
// oldest has ~512 cy to land. Compute capacity 8 B/cy/wave >> 10 B/cy/CU HBM
// share -> memory-bound by construction.

#define MAHAL_ROW(D, MVEC)                                                       \
    {                                                                            \
        const float4* sdv = reinterpret_cast<const float4*>(&sdiff[(D) * 20]);   \
        const float4 dv0 = sdv[0], dv1 = sdv[1], dv2 = sdv[2], dv3 = sdv[3];     \
        const float dsv[16] = {dv0.x, dv0.y, dv0.z, dv0.w,                       \
                               dv1.x, dv1.y, dv1.z, dv1.w,                       \
                               dv2.x, dv2.y, dv2.z, dv2.w,                       \
                               dv3.x, dv3.y, dv3.z, dv3.w};                      \
        _Pragma("unroll")                                                        \
        for (int b = 0; b < NB; ++b) {                                           \
            const float s = dsv[b];                                              \
            acc[b].x = fmaf((MVEC).x, s, acc[b].x);                              \
            acc[b].y = fmaf((MVEC).y, s, acc[b].y);                              \
            acc[b].z = fmaf((MVEC).z, s, acc[b].z);                              \
            acc[b].w = fmaf((MVEC).w, s, acc[b].w);                              \
        }                                                                        \
    }

__global__ __launch_bounds__(256, 2)
void mahal_kernel(const float* __restrict__ inputs,   // [16][3136][256]
                  const float* __restrict__ mean,     // [3136][256]
                  const float* __restrict__ cvar,     // [3136][256][256]
                  float* __restrict__ mask_small)     // [16][3136]
{
    const int p    = blockIdx.x;
    const int tid  = threadIdx.x;
    const int lane = tid & 63;
    const int w    = tid >> 6;

    // diff staged as [c][b] with stride 20 floats (80 B -> 16B aligned rows).
    // Main-loop reads are wave-uniform float4 -> LDS broadcast, conflict-free.
    __shared__ float sdiff[CH * 20];
    __shared__ float sred[4][16];

    const float* mrow_mean = mean + (size_t)p * CH;

    {
        const float mv = mrow_mean[tid];
        #pragma unroll
        for (int b = 0; b < NB; ++b) {
            sdiff[tid * 20 + b] = inputs[((size_t)b * HWPIX + p) * CH + tid] - mv;
        }
    }
    __syncthreads();

    const int c4   = lane * 4;
    const int row0 = w << 6;
    // per-wave base pointer computed ONCE; loop addressing is int offsets only
    const float* Mb = cvar + (size_t)p * CH * CH + (size_t)row0 * CH + c4;

    float4 acc[NB];
    #pragma unroll
    for (int b = 0; b < NB; ++b) acc[b] = make_float4(0.f, 0.f, 0.f, 0.f);

    // rotating prefetch registers: mr[i] holds row (kk + i)
    float4 mr[4];
    #pragma unroll
    for (int i = 0; i < 4; ++i)
        mr[i] = *reinterpret_cast<const float4*>(Mb + i * CH);

    // kk = 0,4,...,56 : compute rows kk..kk+3, prefetch rows kk+4..kk+7 (<=63).
    // NO outer unroll: keeps register pressure low; 4 loads in flight regardless.
    #pragma unroll 1
    for (int kk = 0; kk < 60; kk += 4) {
        #pragma unroll
        for (int i = 0; i < 4; ++i) {
            const float4 m = mr[i];
            mr[i] = *reinterpret_cast<const float4*>(Mb + (kk + 4 + i) * CH);
            MAHAL_ROW(row0 + kk + i, m)
        }
    }
    // peeled tail: rows 60..63, no prefetch (avoids OOB read past cvar)
    #pragma unroll
    for (int i = 0; i < 4; ++i) {
        MAHAL_ROW(row0 + 60 + i, mr[i])
    }

    // epilogue: q[b] = sum_c acc[b][c] * diff[b][c] (re-read diff coalesced, L2-hot)
    const float4 mn = *reinterpret_cast<const float4*>(mrow_mean + c4);
    float q[NB];
    #pragma unroll
    for (int b = 0; b < NB; ++b) {
        const float4 f = *reinterpret_cast<const float4*>(inputs + ((size_t)b * HWPIX + p) * CH + c4);
        const float4 df = make_float4(f.x - mn.x, f.y - mn.y, f.z - mn.z, f.w - mn.w);
        q[b] = acc[b].x * df.x + acc[b].y * df.y + acc[b].z * df.z + acc[b].w * df.w;
    }

    // 64-lane butterfly reduce per b, then cross-wave via LDS
    #pragma unroll
    for (int b = 0; b < NB; ++b) {
        float v = q[b];
        for (int off = 32; off > 0; off >>= 1) v += __shfl_xor(v, off, 64);
        if (lane == 0) sred[w][b] = v;
    }
    __syncthreads();
    if (tid < NB) {
        const float s = sred[0][tid] + sred[1][tid] + sred[2][tid] + sred[3][tid];
        mask_small[(size_t)tid * HWPIX + p] = sqrtf(fmaxf(s, 0.0f));
    }
}

// ---------------- Kernel 2: fused resize(56->224) + blurH + blurW + max ----------
// grid = (14 y-tiles, 16 batches) = 224 blocks, block = 256 threads.
// TY=16: halo redundancy (TY+32)/TY = 3x (was 9x at TY=4 -> tail regressed).
// Stage resized rows [y0-16, y0+TY+16) in LDS (bilinear straight from mask_small,
// 12.5 KB/batch, L1/L2-resident), H-blur into LDS, W-blur to output + max.
__global__ void tail_kernel(const float* __restrict__ small_,   // [16][3136]
                            float* __restrict__ mask_out,       // [16][224][224]
                            float* __restrict__ score)          // [16]
{
    const int b   = blockIdx.y;
    const int y0  = blockIdx.x * TY;
    const int tid = threadIdx.x;

    __shared__ float S[TY + 32][IMG];   // resized rows (reflected)  43.0 KB
    __shared__ float Hb[TY][IMG];       // H-blurred rows            14.3 KB
    __shared__ float m4[4];

    const float* s = small_ + (size_t)b * HWPIX;

    // stage resized rows y0-16 .. y0+TY+15  ((TY+32) x 224 values)
    for (int idx = tid; idx < (TY + 32) * IMG; idx += 256) {
        const int r = idx / IMG;
        const int x = idx - r * IMG;
        int y = y0 - 16 + r;                          // in [-16, 239]
        y = y < 0 ? -y : (y > 223 ? 446 - y : y);     // reflect-101
        float fy = y * 0.25f - 0.375f;
        float fx = x * 0.25f - 0.375f;
        fy = fminf(fmaxf(fy, 0.0f), 55.0f);
        fx = fminf(fmaxf(fx, 0.0f), 55.0f);
        const int iy0 = min((int)fy, 54);
        const int ix0 = min((int)fx, 54);
        const float wy = fy - iy0;
        const float wx = fx - ix0;
        const float v00 = s[iy0 * 56 + ix0];
        const float v01 = s[iy0 * 56 + ix0 + 1];
        const float v10 = s[(iy0 + 1) * 56 + ix0];
        const float v11 = s[(iy0 + 1) * 56 + ix0 + 1];
        const float v0 = v00 + wx * (v01 - v00);
        const float v1 = v10 + wx * (v11 - v10);
        S[r][x] = v0 + wy * (v1 - v0);
    }
    __syncthreads();

    // blur along H: Hb[ty][x] = sum_i GW[i] * S[ty+i][x]
    for (int idx = tid; idx < TY * IMG; idx += 256) {
        const int ty = idx / IMG;
        const int x  = idx - ty * IMG;
        float a = 0.f;
        #pragma unroll
        for (int i = 0; i < 33; ++i) a = fmaf(GW[i], S[ty + i][x], a);
        Hb[ty][x] = a;
    }
    __syncthreads();

    // blur along W + store + max
    float vmax = 0.f;
    for (int idx = tid; idx < TY * IMG; idx += 256) {
        const int ty = idx / IMG;
        const int x  = idx - ty * IMG;
        float a = 0.f;
        #pragma unroll
        for (int i = 0; i < 33; ++i) {
            int xx = x - 16 + i;
            xx = xx < 0 ? -xx : (xx > 223 ? 446 - xx : xx);
            a = fmaf(GW[i], Hb[ty][xx], a);
        }
        mask_out[((size_t)b * IMG + (y0 + ty)) * IMG + x] = a;
        vmax = fmaxf(vmax, a);
    }

    // block max -> atomicMax (values >= 0, int-bit compare is monotone)
    for (int off = 32; off > 0; off >>= 1) vmax = fmaxf(vmax, __shfl_xor(vmax, off, 64));
    const int lane = tid & 63;
    const int wv   = tid >> 6;
    if (lane == 0) m4[wv] = vmax;
    __syncthreads();
    if (tid == 0) {
        const float mm = fmaxf(fmaxf(m4[0], m4[1]), fmaxf(m4[2], m4[3]));
        atomicMax(reinterpret_cast<int*>(score) + b, __float_as_int(mm));
    }
}

// ---------------- Kernel 0: init score to 0 (d_out is poisoned 0xAA) ----------------
__global__ void init_score(float* __restrict__ score)
{
    if (threadIdx.x < NB) score[threadIdx.x] = 0.0f;
}

extern "C" void kernel_launch(void* const* d_in, const int* in_sizes, int n_in,
                              void* d_out, int out_size, void* d_ws, size_t ws_size,
                              hipStream_t stream)
{
    const float* inputs = (const float*)d_in[0];   // [16][3136][256]
    const float* mean   = (const float*)d_in[1];   // [3136][256]
    const float* cvar   = (const float*)d_in[2];   // [3136][256][256]

    float* score    = (float*)d_out;               // [16]
    float* mask_out = (float*)d_out + NB;          // [16][224][224]

    float* mask_small = (float*)d_ws;              // 16*3136 floats

    init_score  <<<1, 64, 0, stream>>>(score);
    mahal_kernel<<<HWPIX, 256, 0, stream>>>(inputs, mean, cvar, mask_small);
    tail_kernel <<<dim3(IMG / TY, NB), 256, 0, stream>>>(mask_small, mask_out, score);
}